// Round 10
// baseline (636.704 us; speedup 1.0000x reference)
//
#include <hip/hip_runtime.h>
#include <hip/hip_bf16.h>

#define HID 128
#define NHEAD 4

typedef __attribute__((ext_vector_type(8))) short bf16x8;
typedef __attribute__((ext_vector_type(4))) float f32x4;
typedef __attribute__((ext_vector_type(2))) float f32x2;
typedef __attribute__((ext_vector_type(4))) int i32x4;

// ---------------- CSR build ----------------
// XCD-partitioned histogram; nt-vector edge stream (no L2 pollution).
__global__ __launch_bounds__(256) void count_deg_xcd(const int* __restrict__ dst,
                                                     int* __restrict__ deg, int E, int n) {
    int grp = blockIdx.x & 7;
    int blk = blockIdx.x >> 3;
    int nblk = gridDim.x >> 3;
    int lo = (int)(((long long)n * grp) >> 3);
    int hi = (int)(((long long)n * (grp + 1)) >> 3);
    int E4 = E >> 2;
    const i32x4* dst4 = (const i32x4*)dst;
    for (int i = blk * 256 + threadIdx.x; i < E4; i += nblk * 256) {
        i32x4 d4 = __builtin_nontemporal_load(&dst4[i]);
#pragma unroll
        for (int j = 0; j < 4; ++j) {
            int d = d4[j];
            if (d >= lo && d < hi) atomicAdd(&deg[d], 1);
        }
    }
    if (blk == 0) {
        for (int i = (E & ~3) + threadIdx.x; i < E; i += 256) {
            int d = dst[i];
            if (d >= lo && d < hi) atomicAdd(&deg[d], 1);
        }
    }
}

__global__ void block_sums(const int* __restrict__ deg, int* __restrict__ bsum, int n) {
    __shared__ int sbuf[512];
    int tid = threadIdx.x;
    int i = blockIdx.x * 512 + tid;
    sbuf[tid] = (i < n) ? deg[i] : 0;
    __syncthreads();
    for (int d = 256; d > 0; d >>= 1) {
        if (tid < d) sbuf[tid] += sbuf[tid + d];
        __syncthreads();
    }
    if (tid == 0) bsum[blockIdx.x] = sbuf[0];
}

__global__ void scan_partials(const int* __restrict__ bsum, int* __restrict__ bpre, int P) {
    __shared__ int buf[128];
    int tid = threadIdx.x; // 128 threads, P <= 128
    int v = (tid < P) ? bsum[tid] : 0;
    buf[tid] = v;
    __syncthreads();
    for (int d = 1; d < 128; d <<= 1) {
        int t = (tid >= d) ? buf[tid - d] : 0;
        __syncthreads();
        buf[tid] += t;
        __syncthreads();
    }
    if (tid < P) bpre[tid] = buf[tid] - v; // exclusive
}

__global__ void scan_blocks(const int* __restrict__ deg, const int* __restrict__ bpre,
                            int* __restrict__ offs, int* __restrict__ woff, int n) {
    __shared__ int sbuf[512];
    int tid = threadIdx.x;
    int i = blockIdx.x * 512 + tid;
    int v = (i < n) ? deg[i] : 0;
    sbuf[tid] = v;
    __syncthreads();
    for (int d = 1; d < 512; d <<= 1) {
        int t = (tid >= d) ? sbuf[tid - d] : 0;
        __syncthreads();
        sbuf[tid] += t;
        __syncthreads();
    }
    if (i < n) {
        int incl = bpre[blockIdx.x] + sbuf[tid];
        offs[i + 1] = incl;
        woff[i] = incl - v;
    }
    if (i == 0) offs[0] = 0;
}

// XCD-partitioned scatter; nt-vector edge streams keep csr write lines in L2
// until full (write-combining), since group's csr region (~E/8*4B) fits in L2.
__global__ __launch_bounds__(256) void fill_csr_xcd(
    const int* __restrict__ src, const int* __restrict__ dst,
    int* __restrict__ woff, int* __restrict__ csr_src, int E, int n) {
    int grp = blockIdx.x & 7;
    int blk = blockIdx.x >> 3;
    int nblk = gridDim.x >> 3;
    int lo = (int)(((long long)n * grp) >> 3);
    int hi = (int)(((long long)n * (grp + 1)) >> 3);
    int E4 = E >> 2;
    const i32x4* dst4 = (const i32x4*)dst;
    const i32x4* src4 = (const i32x4*)src;
    for (int i = blk * 256 + threadIdx.x; i < E4; i += nblk * 256) {
        i32x4 d4 = __builtin_nontemporal_load(&dst4[i]);
        i32x4 s4 = __builtin_nontemporal_load(&src4[i]);
#pragma unroll
        for (int j = 0; j < 4; ++j) {
            int d = d4[j];
            if (d >= lo && d < hi) {
                int pos = atomicAdd(&woff[d], 1);
                csr_src[pos] = s4[j];
            }
        }
    }
    if (blk == 0) {
        for (int i = (E & ~3) + threadIdx.x; i < E; i += 256) {
            int d = dst[i];
            if (d >= lo && d < hi) {
                int pos = atomicAdd(&woff[d], 1);
                csr_src[pos] = src[i];
            }
        }
    }
}

// ---------------- helpers ----------------
__device__ __forceinline__ unsigned pack2_bf16_rne(float lo, float hi) {
    unsigned a = __float_as_uint(lo);
    a = (a + 0x7fffu + ((a >> 16) & 1u)) >> 16;
    unsigned b = __float_as_uint(hi);
    b = (b + 0x7fffu + ((b >> 16) & 1u)) & 0xffff0000u;
    return a | b;
}

__device__ __forceinline__ unsigned short bf16_rne(float x) {
    unsigned u = __float_as_uint(x);
    u = (u + 0x7fffu + ((u >> 16) & 1u)) >> 16;
    return (unsigned short)u;
}

__device__ __forceinline__ f32x2 unpack_bf(unsigned u) {
    f32x2 r;
    r.x = __uint_as_float(u << 16);
    r.y = __uint_as_float(u & 0xffff0000u);
    return r;
}

__device__ __forceinline__ f32x2 leaky2(f32x2 q) {
    return __builtin_elementwise_max(q, q * 0.2f);
}

// 4-lane group sum via DPP: xor1 (quad_perm[1,0,3,2]=0xB1), xor2
// (quad_perm[2,3,0,1]=0x4E).
__device__ __forceinline__ float row_sum4(float x) {
    x += __int_as_float(__builtin_amdgcn_update_dpp(0, __float_as_int(x), 0xB1, 0xF, 0xF, true));
    x += __int_as_float(__builtin_amdgcn_update_dpp(0, __float_as_int(x), 0x4E, 0xF, 0xF, true));
    return x;
}

// Transpose+convert 8 [128,128] f32 weight mats to bf16 [N][K]
__global__ void prep_weights(const float* __restrict__ W_src, const float* __restrict__ W_dst,
                             const float* __restrict__ W1, const float* __restrict__ W2,
                             unsigned short* __restrict__ Wt) {
    int mat = blockIdx.x; // 0..7
    const float* Wf = (mat < 3) ? (W_src + (size_t)mat * 16384)
                    : (mat < 6) ? (W_dst + (size_t)(mat - 3) * 16384)
                    : (mat == 6) ? W1 : W2;
    unsigned short* out = Wt + (size_t)mat * 16384;
    for (int idx = threadIdx.x; idx < 16384; idx += blockDim.x) {
        int k = idx >> 7, nn = idx & 127;
        out[nn * 128 + k] = bf16_rne(Wf[idx]);
    }
}

// ---------------- vector GEMM (K=32 input projection) ----------------
#define GR 64
template <int K, bool RELU, bool F32OUT, bool BF16OUT>
__global__ __launch_bounds__(256) void gemm_k(const float* __restrict__ A,
                                              const float* __restrict__ W,
                                              const float* __restrict__ bias,
                                              float* __restrict__ Cf,
                                              unsigned short* __restrict__ C16, int n) {
    __shared__ __align__(16) float a_sh[GR * K];
    const int tid = threadIdx.x;
    const int tx = tid & 31;
    const int ty = tid >> 5;
    const int r0 = blockIdx.x * GR;

    for (int i = tid * 4; i < GR * K; i += 1024) {
        int r = i / K, k = i % K;
        int gr = r0 + r;
        float4 v = make_float4(0.f, 0.f, 0.f, 0.f);
        if (gr < n) v = *(const float4*)&A[(size_t)gr * K + k];
        *(float4*)&a_sh[i] = v;
    }
    __syncthreads();

    float4 acc[8];
#pragma unroll
    for (int r = 0; r < 8; ++r) acc[r] = make_float4(0.f, 0.f, 0.f, 0.f);

    const float* ab = &a_sh[ty * 8 * K];
    const float* wb = &W[tx * 4];

    for (int k = 0; k < K; k += 4) {
        float4 w0 = *(const float4*)&wb[(size_t)(k + 0) * 128];
        float4 w1 = *(const float4*)&wb[(size_t)(k + 1) * 128];
        float4 w2 = *(const float4*)&wb[(size_t)(k + 2) * 128];
        float4 w3 = *(const float4*)&wb[(size_t)(k + 3) * 128];
#pragma unroll
        for (int r = 0; r < 8; ++r) {
            float4 a4 = *(const float4*)&ab[r * K + k];
            acc[r].x = fmaf(a4.x, w0.x, acc[r].x);
            acc[r].y = fmaf(a4.x, w0.y, acc[r].y);
            acc[r].z = fmaf(a4.x, w0.z, acc[r].z);
            acc[r].w = fmaf(a4.x, w0.w, acc[r].w);
            acc[r].x = fmaf(a4.y, w1.x, acc[r].x);
            acc[r].y = fmaf(a4.y, w1.y, acc[r].y);
            acc[r].z = fmaf(a4.y, w1.z, acc[r].z);
            acc[r].w = fmaf(a4.y, w1.w, acc[r].w);
            acc[r].x = fmaf(a4.z, w2.x, acc[r].x);
            acc[r].y = fmaf(a4.z, w2.y, acc[r].y);
            acc[r].z = fmaf(a4.z, w2.z, acc[r].z);
            acc[r].w = fmaf(a4.z, w2.w, acc[r].w);
            acc[r].x = fmaf(a4.w, w3.x, acc[r].x);
            acc[r].y = fmaf(a4.w, w3.y, acc[r].y);
            acc[r].z = fmaf(a4.w, w3.z, acc[r].z);
            acc[r].w = fmaf(a4.w, w3.w, acc[r].w);
        }
    }

    float4 b4 = *(const float4*)&bias[tx * 4];
#pragma unroll
    for (int r = 0; r < 8; ++r) {
        int gr = r0 + ty * 8 + r;
        if (gr < n) {
            float4 o;
            o.x = acc[r].x + b4.x;
            o.y = acc[r].y + b4.y;
            o.z = acc[r].z + b4.z;
            o.w = acc[r].w + b4.w;
            if (RELU) {
                o.x = fmaxf(o.x, 0.f); o.y = fmaxf(o.y, 0.f);
                o.z = fmaxf(o.z, 0.f); o.w = fmaxf(o.w, 0.f);
            }
            if (F32OUT) *(float4*)&Cf[(size_t)gr * 128 + tx * 4] = o;
            if (BF16OUT) {
                uint2 st;
                st.x = pack2_bf16_rne(o.x, o.y);
                st.y = pack2_bf16_rne(o.z, o.w);
                *(uint2*)&C16[(size_t)gr * 128 + tx * 4] = st;
            }
        }
    }
}

// ---------------- MFMA GEMM (single output) ----------------
template <bool RELU, bool F32OUT, bool BF16OUT>
__global__ __launch_bounds__(256) void gemm_mfma(
    const unsigned short* __restrict__ A16,
    const unsigned short* __restrict__ Bt16,
    const float* __restrict__ bias,
    float* __restrict__ Cf, unsigned short* __restrict__ C16, int n) {
    const int wave = threadIdx.x >> 6;
    const int lane = threadIdx.x & 63;
    const int r = lane & 15, g = lane >> 4;
    const int m0 = blockIdx.x * 64 + wave * 16;
    int ra = m0 + r; if (ra > n - 1) ra = n - 1;
    const bf16x8* Arow = (const bf16x8*)(A16 + (size_t)ra * 128);
    bf16x8 a0 = Arow[g];
    bf16x8 a1 = Arow[4 + g];
    bf16x8 a2 = Arow[8 + g];
    bf16x8 a3 = Arow[12 + g];
#pragma unroll
    for (int ct = 0; ct < 8; ++ct) {
        const bf16x8* Brow = (const bf16x8*)(Bt16 + (size_t)(ct * 16 + r) * 128);
        f32x4 acc = {0.f, 0.f, 0.f, 0.f};
        acc = __builtin_amdgcn_mfma_f32_16x16x32_bf16(a0, Brow[g], acc, 0, 0, 0);
        acc = __builtin_amdgcn_mfma_f32_16x16x32_bf16(a1, Brow[4 + g], acc, 0, 0, 0);
        acc = __builtin_amdgcn_mfma_f32_16x16x32_bf16(a2, Brow[8 + g], acc, 0, 0, 0);
        acc = __builtin_amdgcn_mfma_f32_16x16x32_bf16(a3, Brow[12 + g], acc, 0, 0, 0);
        const int col = ct * 16 + r;
        const float bcol = bias[col];
#pragma unroll
        for (int j = 0; j < 4; ++j) {
            int row = m0 + g * 4 + j;
            if (row < n) {
                float v = acc[j] + bcol;
                if (RELU) v = fmaxf(v, 0.f);
                if (F32OUT) Cf[(size_t)row * 128 + col] = v;
                if (BF16OUT) C16[(size_t)row * 128 + col] = bf16_rne(v);
            }
        }
    }
}

// ---------------- MFMA GEMM dual: A read once, two B mats, both bf16 out ----------------
__global__ __launch_bounds__(256) void gemm_mfma_dual(
    const unsigned short* __restrict__ A16,
    const unsigned short* __restrict__ B1t, const unsigned short* __restrict__ B2t,
    const float* __restrict__ bias1, const float* __restrict__ bias2,
    unsigned short* __restrict__ C1, unsigned short* __restrict__ C2, int n) {
    const int wave = threadIdx.x >> 6;
    const int lane = threadIdx.x & 63;
    const int r = lane & 15, g = lane >> 4;
    const int m0 = blockIdx.x * 64 + wave * 16;
    int ra = m0 + r; if (ra > n - 1) ra = n - 1;
    const bf16x8* Arow = (const bf16x8*)(A16 + (size_t)ra * 128);
    bf16x8 a0 = Arow[g];
    bf16x8 a1 = Arow[4 + g];
    bf16x8 a2 = Arow[8 + g];
    bf16x8 a3 = Arow[12 + g];
#pragma unroll
    for (int ct = 0; ct < 8; ++ct) {
        const int col = ct * 16 + r;
        {
            const bf16x8* Brow = (const bf16x8*)(B1t + (size_t)col * 128);
            f32x4 acc = {0.f, 0.f, 0.f, 0.f};
            acc = __builtin_amdgcn_mfma_f32_16x16x32_bf16(a0, Brow[g], acc, 0, 0, 0);
            acc = __builtin_amdgcn_mfma_f32_16x16x32_bf16(a1, Brow[4 + g], acc, 0, 0, 0);
            acc = __builtin_amdgcn_mfma_f32_16x16x32_bf16(a2, Brow[8 + g], acc, 0, 0, 0);
            acc = __builtin_amdgcn_mfma_f32_16x16x32_bf16(a3, Brow[12 + g], acc, 0, 0, 0);
            const float bcol = bias1[col];
#pragma unroll
            for (int j = 0; j < 4; ++j) {
                int row = m0 + g * 4 + j;
                if (row < n) C1[(size_t)row * 128 + col] = bf16_rne(acc[j] + bcol);
            }
        }
        {
            const bf16x8* Brow = (const bf16x8*)(B2t + (size_t)col * 128);
            f32x4 acc = {0.f, 0.f, 0.f, 0.f};
            acc = __builtin_amdgcn_mfma_f32_16x16x32_bf16(a0, Brow[g], acc, 0, 0, 0);
            acc = __builtin_amdgcn_mfma_f32_16x16x32_bf16(a1, Brow[4 + g], acc, 0, 0, 0);
            acc = __builtin_amdgcn_mfma_f32_16x16x32_bf16(a2, Brow[8 + g], acc, 0, 0, 0);
            acc = __builtin_amdgcn_mfma_f32_16x16x32_bf16(a3, Brow[12 + g], acc, 0, 0, 0);
            const float bcol = bias2[col];
#pragma unroll
            for (int j = 0; j < 4; ++j) {
                int row = m0 + g * 4 + j;
                if (row < n) C2[(size_t)row * 128 + col] = bf16_rne(acc[j] + bcol);
            }
        }
    }
}

// ---------------- fused GATv2 aggregate + residuals + LayerNorm + ReLU ----------------
// one wave per node, FOUR edges per wave: quarter q = lane>>4 owns edge i+q.
// lane owns 8 features f0 = (lane&15)*8; head = (lane&15)>>2 -> 4-lane groups.
// log2-domain scores, packed f32 math, shared reference max, software-pipelined
// gather (index+row prefetched one iteration ahead), masked single-pass tail.
__global__ __launch_bounds__(256) void gat_aggregate(
    const float* __restrict__ h,             // [n,128] f32 (residual)
    const unsigned short* __restrict__ hs16, // [n,128] bf16 (gathered)
    const unsigned short* __restrict__ hd16, // [n,128] bf16 (scores only)
    const int* __restrict__ offs,
    const int* __restrict__ csr_src,
    const float* __restrict__ attn,
    const float* __restrict__ ln_g, const float* __restrict__ ln_b,
    float* __restrict__ h_out, unsigned* __restrict__ h16_out, int n) {
    int v = (blockIdx.x * blockDim.x + threadIdx.x) >> 6;
    int lane = threadIdx.x & 63;
    if (v >= n) return;
    const int lh = lane & 15;
    const int quarter = lane >> 4;
    const int f0 = lh * 8;
    const unsigned fb = (unsigned)lh << 4; // byte offset into 256B bf16 row

    const float L2E = 1.4426950408889634f;
    f32x2 av0, av1, av2, av3;
    {
        float4 aa = *(const float4*)&attn[f0];
        float4 ab = *(const float4*)&attn[f0 + 4];
        av0 = (f32x2){aa.x, aa.y} * L2E; av1 = (f32x2){aa.z, aa.w} * L2E;
        av2 = (f32x2){ab.x, ab.y} * L2E; av3 = (f32x2){ab.z, ab.w} * L2E;
    }
    const char* hsb = (const char*)hs16;
    f32x2 hd0, hd1, hd2, hd3;
    {
        uint4 wd = *(const uint4*)((const char*)hd16 + ((size_t)(unsigned)v << 8) + fb);
        hd0 = unpack_bf(wd.x); hd1 = unpack_bf(wd.y);
        hd2 = unpack_bf(wd.z); hd3 = unpack_bf(wd.w);
    }
    // self-loop (identical in all quarters)
    uint4 wv = *(const uint4*)(hsb + ((size_t)(unsigned)v << 8) + fb);
    f32x2 sv0 = unpack_bf(wv.x), sv1 = unpack_bf(wv.y);
    f32x2 sv2 = unpack_bf(wv.z), sv3 = unpack_bf(wv.w);
    float m;
    {
        f32x2 q0 = leaky2(sv0 + hd0), q1 = leaky2(sv1 + hd1);
        f32x2 q2 = leaky2(sv2 + hd2), q3 = leaky2(sv3 + hd3);
        f32x2 dt = q0 * av0; dt += q1 * av1; dt += q2 * av2; dt += q3 * av3;
        m = row_sum4(dt.x + dt.y);
    }
    const bool q0lane = (quarter == 0);
    float s = q0lane ? 1.f : 0.f;
    f32x2 acc0 = q0lane ? sv0 : (f32x2){0.f, 0.f};
    f32x2 acc1 = q0lane ? sv1 : (f32x2){0.f, 0.f};
    f32x2 acc2 = q0lane ? sv2 : (f32x2){0.f, 0.f};
    f32x2 acc3 = q0lane ? sv3 : (f32x2){0.f, 0.f};

    int beg = offs[v], end = offs[v + 1];
    int end4 = beg + ((end - beg) & ~3);

    auto process = [&](uint4 w) {
        f32x2 g0 = unpack_bf(w.x), g1 = unpack_bf(w.y);
        f32x2 g2 = unpack_bf(w.z), g3 = unpack_bf(w.w);
        f32x2 p0 = leaky2(g0 + hd0), p1 = leaky2(g1 + hd1);
        f32x2 p2 = leaky2(g2 + hd2), p3 = leaky2(g3 + hd3);
        f32x2 dt = p0 * av0; dt += p1 * av1; dt += p2 * av2; dt += p3 * av3;
        float sc = row_sum4(dt.x + dt.y);
        float d0 = sc - m;
        if (__builtin_expect(__any(d0 > 8.f), 0)) {
            float dmx = fmaxf(d0, __shfl_xor(d0, 16));
            dmx = fmaxf(dmx, __shfl_xor(dmx, 32));
            float mn = m + fmaxf(dmx, 0.f);
            float rr = exp2f(m - mn);
            s *= rr; acc0 *= rr; acc1 *= rr; acc2 *= rr; acc3 *= rr;
            m = mn; d0 = sc - m;
        }
        float e = exp2f(d0);
        s += e;
        acc0 += g0 * e; acc1 += g1 * e; acc2 += g2 * e; acc3 += g3 * e;
    };

    if (end4 > beg) {
        // software pipeline: gather for iter k+1 issued before processing iter k
        uint4 w = *(const uint4*)(hsb + ((size_t)(unsigned)csr_src[beg + quarter] << 8) + fb);
        int un = (beg + 4 < end4) ? csr_src[beg + 4 + quarter] : 0;
        for (int i = beg + 4; i < end4; i += 4) {
            uint4 wn = *(const uint4*)(hsb + ((size_t)(unsigned)un << 8) + fb);
            if (i + 4 < end4) un = csr_src[i + 4 + quarter];
            process(w);
            w = wn;
        }
        process(w);
    }
    if (end4 < end) {
        // masked tail: one quad iteration, quarters >= remainder contribute 0
        int idx = end4 + quarter;
        bool act = idx < end;
        int u = csr_src[act ? idx : end4];
        uint4 w = *(const uint4*)(hsb + ((size_t)(unsigned)u << 8) + fb);
        f32x2 g0 = unpack_bf(w.x), g1 = unpack_bf(w.y);
        f32x2 g2 = unpack_bf(w.z), g3 = unpack_bf(w.w);
        f32x2 p0 = leaky2(g0 + hd0), p1 = leaky2(g1 + hd1);
        f32x2 p2 = leaky2(g2 + hd2), p3 = leaky2(g3 + hd3);
        f32x2 dt = p0 * av0; dt += p1 * av1; dt += p2 * av2; dt += p3 * av3;
        float sc = row_sum4(dt.x + dt.y);
        float d0 = sc - m;
        float d0m = act ? d0 : -1e30f;
        if (__builtin_expect(__any(d0m > 8.f), 0)) {
            float dmx = fmaxf(d0m, __shfl_xor(d0m, 16));
            dmx = fmaxf(dmx, __shfl_xor(dmx, 32));
            float mn = m + fmaxf(dmx, 0.f);
            float rr = exp2f(m - mn);
            s *= rr; acc0 *= rr; acc1 *= rr; acc2 *= rr; acc3 *= rr;
            m = mn; d0 = sc - m;
        }
        float e = act ? exp2f(d0) : 0.f;
        s += e;
        acc0 += g0 * e; acc1 += g1 * e; acc2 += g2 * e; acc3 += g3 * e;
    }
    // cross-quarter merge (shared m -> plain adds)
#pragma unroll
    for (int d = 16; d <= 32; d <<= 1) {
        s += __shfl_xor(s, d);
        acc0.x += __shfl_xor(acc0.x, d); acc0.y += __shfl_xor(acc0.y, d);
        acc1.x += __shfl_xor(acc1.x, d); acc1.y += __shfl_xor(acc1.y, d);
        acc2.x += __shfl_xor(acc2.x, d); acc2.y += __shfl_xor(acc2.y, d);
        acc3.x += __shfl_xor(acc3.x, d); acc3.y += __shfl_xor(acc3.y, d);
    }
    float inv = 1.0f / (s + 1e-9f);

    f32x2 hv0, hv1, hv2, hv3;
    {
        float4 ha = *(const float4*)&h[(size_t)v * 128 + f0];
        float4 hb = *(const float4*)&h[(size_t)v * 128 + f0 + 4];
        hv0 = (f32x2){ha.x, ha.y}; hv1 = (f32x2){ha.z, ha.w};
        hv2 = (f32x2){hb.x, hb.y}; hv3 = (f32x2){hb.z, hb.w};
    }
    f32x2 x0 = acc0 * inv + hv0 * 2.f;
    f32x2 x1 = acc1 * inv + hv1 * 2.f;
    f32x2 x2 = acc2 * inv + hv2 * 2.f;
    f32x2 x3 = acc3 * inv + hv3 * 2.f;

    // LayerNorm: all quarters hold identical x -> 64-lane reduce counts 4x
    f32x2 sum2 = (x0 + x1) + (x2 + x3);
    f32x2 sq2 = x0 * x0 + x1 * x1 + x2 * x2 + x3 * x3;
    float sum = sum2.x + sum2.y, sq = sq2.x + sq2.y;
#pragma unroll
    for (int d = 1; d < 64; d <<= 1) { sum += __shfl_xor(sum, d); sq += __shfl_xor(sq, d); }
    float mu = sum * (1.f / 512.f);
    float var = sq * (1.f / 512.f) - mu * mu;
    float rstd = rsqrtf(var + 1e-5f);
    f32x2 g0v, g1v, g2v, g3v, b0v, b1v, b2v, b3v;
    {
        float4 ga = *(const float4*)&ln_g[f0];
        float4 gb = *(const float4*)&ln_g[f0 + 4];
        float4 ba = *(const float4*)&ln_b[f0];
        float4 bb = *(const float4*)&ln_b[f0 + 4];
        g0v = (f32x2){ga.x, ga.y}; g1v = (f32x2){ga.z, ga.w};
        g2v = (f32x2){gb.x, gb.y}; g3v = (f32x2){gb.z, gb.w};
        b0v = (f32x2){ba.x, ba.y}; b1v = (f32x2){ba.z, ba.w};
        b2v = (f32x2){bb.x, bb.y}; b3v = (f32x2){bb.z, bb.w};
    }
    f32x2 zero = {0.f, 0.f};
    f32x2 y0 = __builtin_elementwise_max((x0 - mu) * rstd * g0v + b0v, zero);
    f32x2 y1 = __builtin_elementwise_max((x1 - mu) * rstd * g1v + b1v, zero);
    f32x2 y2 = __builtin_elementwise_max((x2 - mu) * rstd * g2v + b2v, zero);
    f32x2 y3 = __builtin_elementwise_max((x3 - mu) * rstd * g3v + b3v, zero);
    if (quarter == 0) {
        float* orow = &h_out[(size_t)v * 128 + f0];
        *(float4*)orow = make_float4(y0.x, y0.y, y1.x, y1.y);
        *(float4*)(orow + 4) = make_float4(y2.x, y2.y, y3.x, y3.y);
        uint4 st;
        st.x = pack2_bf16_rne(y0.x, y0.y);
        st.y = pack2_bf16_rne(y1.x, y1.y);
        st.z = pack2_bf16_rne(y2.x, y2.y);
        st.w = pack2_bf16_rne(y3.x, y3.y);
        *(uint4*)((char*)h16_out + ((size_t)v << 8) + fb) = st;
    }
}

// ---------------- epilogue ----------------
__global__ __launch_bounds__(256) void mean_partial(const float4* __restrict__ src,
                                                    float* __restrict__ gacc, size_t n4) {
    int tid = threadIdx.x;
    size_t i = blockIdx.x * (size_t)256 + tid;
    size_t stride = (size_t)gridDim.x * 256;
    float ax = 0.f, ay = 0.f, az = 0.f, aw = 0.f;
    for (; i < n4; i += stride) {
        float4 v = src[i];
        ax += v.x; ay += v.y; az += v.z; aw += v.w;
    }
    __shared__ float4 sb[256];
    sb[tid] = make_float4(ax, ay, az, aw);
    __syncthreads();
    for (int off = 128; off >= 32; off >>= 1) {
        if (tid < off) {
            float4 o = sb[tid + off];
            sb[tid].x += o.x; sb[tid].y += o.y; sb[tid].z += o.z; sb[tid].w += o.w;
        }
        __syncthreads();
    }
    if (tid < 32) {
        float4 a = sb[tid];
        atomicAdd(&gacc[tid * 4 + 0], a.x);
        atomicAdd(&gacc[tid * 4 + 1], a.y);
        atomicAdd(&gacc[tid * 4 + 2], a.z);
        atomicAdd(&gacc[tid * 4 + 3], a.w);
    }
}

__global__ void graph_mean_final(const float* __restrict__ gacc, float* __restrict__ out, int n) {
    int c = threadIdx.x; // 128
    out[c] = gacc[c] / (float)n;
}

__global__ __launch_bounds__(256) void heads_kernel(
    const float* __restrict__ z,
    const float* __restrict__ Wa, const float* __restrict__ ba,
    const float* __restrict__ Wg, const float* __restrict__ bg,
    const float* __restrict__ Wal, const float* __restrict__ bal,
    const float* __restrict__ Wn, const float* __restrict__ bn,
    const float* __restrict__ Wt, const float* __restrict__ bt,
    float* __restrict__ logits, float* __restrict__ spawn, int n) {
    int v = (blockIdx.x * blockDim.x + threadIdx.x) >> 6;
    int lane = threadIdx.x & 63;
    if (v >= n) return;
    int f0 = lane * 2;
    float2 zv = *(const float2*)&z[(size_t)v * 128 + f0];
    float p0 = zv.x * Wa[f0 * 2]     + zv.y * Wa[(f0 + 1) * 2];
    float p1 = zv.x * Wa[f0 * 2 + 1] + zv.y * Wa[(f0 + 1) * 2 + 1];
    float p2 = zv.x * Wg[f0]  + zv.y * Wg[f0 + 1];
    float p3 = zv.x * Wal[f0] + zv.y * Wal[f0 + 1];
    float p4 = zv.x * Wn[f0]  + zv.y * Wn[f0 + 1];
    float p5 = zv.x * Wt[f0]  + zv.y * Wt[f0 + 1];
#pragma unroll
    for (int d = 1; d < 64; d <<= 1) {
        p0 += __shfl_xor(p0, d); p1 += __shfl_xor(p1, d); p2 += __shfl_xor(p2, d);
        p3 += __shfl_xor(p3, d); p4 += __shfl_xor(p4, d); p5 += __shfl_xor(p5, d);
    }
    if (lane == 0) {
        logits[(size_t)v * 2 + 0] = p0 + ba[0];
        logits[(size_t)v * 2 + 1] = p1 + ba[1];
        float gamma = 5.f / (1.f + __expf(-(p2 + bg[0])));
        float alpha = 2.f / (1.f + __expf(-(p3 + bal[0])));
        float noise = 1.f / (1.f + __expf(-(p4 + bn[0])));
        float theta = tanhf(p5 + bt[0]) * 3.14159265358979323846f;
        spawn[(size_t)v * 4 + 0] = gamma;
        spawn[(size_t)v * 4 + 1] = alpha;
        spawn[(size_t)v * 4 + 2] = noise;
        spawn[(size_t)v * 4 + 3] = theta;
    }
}

extern "C" void kernel_launch(void* const* d_in, const int* in_sizes, int n_in,
                              void* d_out, int out_size, void* d_ws, size_t ws_size,
                              hipStream_t stream) {
    const float* node_feats = (const float*)d_in[0];
    const int*   src  = (const int*)d_in[1];
    const int*   dst  = (const int*)d_in[2];
    const float* W_in = (const float*)d_in[3];
    const float* b_in = (const float*)d_in[4];
    const float* W_src = (const float*)d_in[5];
    const float* b_src = (const float*)d_in[6];
    const float* W_dst = (const float*)d_in[7];
    const float* b_dst = (const float*)d_in[8];
    const float* attn  = (const float*)d_in[9];
    const float* ln_g  = (const float*)d_in[10];
    const float* ln_b  = (const float*)d_in[11];
    const float* W1 = (const float*)d_in[12]; const float* b1 = (const float*)d_in[13];
    const float* W2 = (const float*)d_in[14]; const float* b2 = (const float*)d_in[15];
    const float* Wa = (const float*)d_in[16]; const float* ba = (const float*)d_in[17];
    const float* Wg = (const float*)d_in[18]; const float* bg = (const float*)d_in[19];
    const float* Wal = (const float*)d_in[20]; const float* bal = (const float*)d_in[21];
    const float* Wn = (const float*)d_in[22]; const float* bn = (const float*)d_in[23];
    const float* Wt = (const float*)d_in[24]; const float* bt = (const float*)d_in[25];

    const int n = in_sizes[0] / 32;  // 50000
    const int E = in_sizes[1];       // 1600000
    const int P = (n + 511) / 512;

    char* ws = (char*)d_ws;
    size_t off = 0;
    auto alloc = [&](size_t bytes) -> void* {
        void* p = ws + off;
        off = (off + bytes + 255) & ~(size_t)255;
        return p;
    };
    float* Bh0 = (float*)alloc((size_t)n * 128 * 4);
    float* Bh1 = (float*)alloc((size_t)n * 128 * 4);
    float* Bz  = (float*)alloc((size_t)n * 128 * 4);   // z (f32)
    unsigned short* h16  = (unsigned short*)alloc((size_t)n * 128 * 2);
    unsigned short* hs16 = (unsigned short*)alloc((size_t)n * 128 * 2); // also z1
    unsigned short* hd16 = (unsigned short*)alloc((size_t)n * 128 * 2);
    unsigned short* Wt16 = (unsigned short*)alloc((size_t)8 * 16384 * 2);
    int* deg  = (int*)alloc((size_t)n * 4);
    int* offs = (int*)alloc((size_t)(n + 1) * 4);
    int* woff = (int*)alloc((size_t)n * 4);
    int* csr  = (int*)alloc((size_t)E * 4);
    int* bsum = (int*)alloc((size_t)P * 4);
    int* bpre = (int*)alloc((size_t)P * 4);
    float* gacc = (float*)alloc(128 * 4);

    float* out = (float*)d_out;
    float* out_gemb   = out;
    float* out_nemb   = out + 128;
    float* out_logits = out + 128 + (size_t)n * 128;
    float* out_spawn  = out_logits + (size_t)n * 2;

    hipMemsetAsync(deg, 0, (size_t)n * 4, stream);
    hipMemsetAsync(gacc, 0, 128 * 4, stream);

    count_deg_xcd<<<2048, 256, 0, stream>>>(dst, deg, E, n);
    block_sums<<<P, 512, 0, stream>>>(deg, bsum, n);
    scan_partials<<<1, 128, 0, stream>>>(bsum, bpre, P);
    scan_blocks<<<P, 512, 0, stream>>>(deg, bpre, offs, woff, n);
    fill_csr_xcd<<<2048, 256, 0, stream>>>(src, dst, woff, csr, E, n);

    prep_weights<<<8, 256, 0, stream>>>(W_src, W_dst, W1, W2, Wt16);

    int gemm_grid = (n + GR - 1) / GR;
    int mfma_grid = (n + 63) / 64;

    // input projection -> f32 h + bf16 mirror
    gemm_k<32, false, true, true><<<gemm_grid, 256, 0, stream>>>(node_feats, W_in, b_in, Bh0, h16, n);

    float* cur = Bh0;
    for (int l = 0; l < 3; ++l) {
        gemm_mfma_dual<<<mfma_grid, 256, 0, stream>>>(
            h16, Wt16 + (size_t)l * 16384, Wt16 + (size_t)(3 + l) * 16384,
            b_src + l * 128, b_dst + l * 128, hs16, hd16, n);
        float* nxt = (l == 2) ? out_nemb : ((cur == Bh0) ? Bh1 : Bh0);
        gat_aggregate<<<(n + 3) / 4, 256, 0, stream>>>(cur, hs16, hd16, offs, csr,
                                                       attn + l * 128, ln_g + l * 128,
                                                       ln_b + l * 128, nxt, (unsigned*)h16, n);
        cur = nxt;
    }
    // cur == out_nemb (final node embedding, f32); h16 = bf16 mirror

    gemm_mfma<true, false, true><<<mfma_grid, 256, 0, stream>>>(
        h16, Wt16 + (size_t)6 * 16384, b1, nullptr, hs16, n);           // z1 (bf16)
    gemm_mfma<true, true, false><<<mfma_grid, 256, 0, stream>>>(
        hs16, Wt16 + (size_t)7 * 16384, b2, Bz, nullptr, n);            // z (f32)

    mean_partial<<<512, 256, 0, stream>>>((const float4*)out_nemb, gacc, (size_t)n * 32);
    graph_mean_final<<<1, 128, 0, stream>>>(gacc, out_gemb, n);
    heads_kernel<<<(n + 3) / 4, 256, 0, stream>>>(Bz, Wa, ba, Wg, bg, Wal, bal,
                                                  Wn, bn, Wt, bt, out_logits, out_spawn, n);
}